// Round 1
// 1531.187 us; speedup vs baseline: 1.2091x; 1.2091x over previous
//
#include <hip/hip_runtime.h>
#include <stdint.h>

#define B_ 8
#define S_ 1024
#define E_ 1024
#define H_ 16
#define DH_ 64
#define DFF_ 2048
#define KCONV 3

typedef unsigned short u16;
typedef __attribute__((ext_vector_type(8))) short short8;
typedef __attribute__((ext_vector_type(4))) float floatx4;
typedef __attribute__((ext_vector_type(4))) unsigned int uintx4;

__device__ __forceinline__ u16 f2bf(float f) {
  unsigned int u = __builtin_bit_cast(unsigned int, f);
  u += 0x7FFFu + ((u >> 16) & 1u);
  return (u16)(u >> 16);
}
__device__ __forceinline__ float bf2f(u16 x) {
  unsigned int u = ((unsigned int)x) << 16;
  return __builtin_bit_cast(float, u);
}

// load 8 consecutive fp32, round-to-nearest-even to bf16, pack into 16B
__device__ __forceinline__ uintx4 ld8_f32_bf(const float* __restrict__ p) {
  floatx4 a = *(const floatx4*)p;
  floatx4 b = *(const floatx4*)(p + 4);
  uintx4 r;
  r.x = (unsigned)f2bf(a[0]) | ((unsigned)f2bf(a[1]) << 16);
  r.y = (unsigned)f2bf(a[2]) | ((unsigned)f2bf(a[3]) << 16);
  r.z = (unsigned)f2bf(b[0]) | ((unsigned)f2bf(b[1]) << 16);
  r.w = (unsigned)f2bf(b[2]) | ((unsigned)f2bf(b[3]) << 16);
  return r;
}

// async global->LDS, 16B per lane. LDS dest = wave-uniform base + lane*16.
__device__ __forceinline__ void gload16(const void* g, void* l) {
  __builtin_amdgcn_global_load_lds((__attribute__((address_space(1))) void*)g,
                                   (__attribute__((address_space(3))) void*)l,
                                   16, 0, 0);
}

enum { F_BIAS = 1, F_RELU = 2, F_RESID = 4, F_OUTF32 = 8, F_SCALE = 16 };

// NT GEMM: D[m][n] = scale * sum_k A[m][k] * W[n][k] (+bias[n]) (+resid[m][n])
// AF32/WF32: operand stored as fp32, converted to bf16 during (register) LDS staging.
// Pure-bf16 instantiations (GL) use global_load_lds width-16 with LINEAR LDS
// (LDP=64; accepts 16-way read conflicts -- m97 regime, gload gain dominates).
// TAPS>1: causal-conv mode, A row for tap t is (s + t - (TAPS-1)); rows with
// s+t-(TAPS-1) < 0 are zeroed AFTER staging (gload can't zero-fill; the stale
// loads stay inside the workspace so they're safe to fetch then overwrite).
// Batched via blockIdx.z: base offsets (z/zdiv)*S1 + (z%zdiv)*S2.
template <int WR, int WC, int TAPS, int FLAGS, bool AF32, bool WF32>
__global__ void __launch_bounds__(256, 2)
gemm_kernel(const void* __restrict__ A, long aS1, long aS2,
            const void* __restrict__ W, long wS1, long wS2,
            const float* __restrict__ bias, const float* __restrict__ resid,
            void* __restrict__ Cout, long cS1, long cS2,
            int zdiv, int lda, int ldw, int ldc, int Kin, float scale) {
  constexpr bool GL = !AF32 && !WF32;   // both operands bf16 -> global_load_lds path
  constexpr int BM = WR * 64, BN = WC * 64, BK = 64;
  constexpr int LDP = GL ? BK : BK + 8;
  __shared__ __align__(16) u16 As[BM * LDP];
  __shared__ __align__(16) u16 Bs[BN * LDP];

  const int z = blockIdx.z;
  const int zq = z / zdiv, zr = z % zdiv;
  const u16* Ab16 = (const u16*)A + zq * aS1 + zr * aS2;
  const float* Ab32 = (const float*)A + zq * aS1 + zr * aS2;
  const u16* Wb16 = (const u16*)W + zq * wS1 + zr * wS2;
  const float* Wb32 = (const float*)W + zq * wS1 + zr * wS2;
  const long cOff = zq * cS1 + zr * cS2;

  const int m0 = blockIdx.y * BM;
  const int n0 = blockIdx.x * BN;
  const int tid = threadIdx.x;
  const int lane = tid & 63;
  const int wave = tid >> 6;
  const int wrow = wave / WC;
  const int wcol = wave % WC;
  const int lm = lane & 15;  // MFMA m/n index
  const int lk = lane >> 4;  // MFMA k-quad

  floatx4 acc[4][4];
#pragma unroll
  for (int r = 0; r < 4; ++r)
#pragma unroll
    for (int c = 0; c < 4; ++c) acc[r][c] = floatx4{0.f, 0.f, 0.f, 0.f};

  for (int t = 0; t < TAPS; ++t) {
    for (int k0 = 0; k0 < Kin; k0 += BK) {
      __syncthreads();
      if constexpr (GL) {
// A tile (BM x BK) via async direct-to-LDS, 4KB per iter (256 lanes x 16B)
#pragma unroll
        for (int it = 0; it < BM * BK / 8 / 256; ++it) {
          int c = tid + it * 256;
          int row = c >> 3;
          int kc = (c & 7) << 3;
          long arow = m0 + row;
          if (TAPS > 1) arow += t - (TAPS - 1);  // may go <0: stale-but-safe, zeroed below
          gload16(Ab16 + arow * (long)lda + k0 + kc,
                  (char*)As + it * 4096 + wave * 1024);
        }
// W tile (BN x BK)
#pragma unroll
        for (int it = 0; it < BN * BK / 8 / 256; ++it) {
          int c = tid + it * 256;
          int row = c >> 3;
          int kc = (c & 7) << 3;
          long off = (long)(n0 + row) * ldw + (long)t * Kin + k0 + kc;
          gload16(Wb16 + off, (char*)Bs + it * 4096 + wave * 1024);
        }
      } else {
// register staging (fp32 operands converted inline); padded LDS
#pragma unroll
        for (int it = 0; it < BM * BK / 8 / 256; ++it) {
          int c = tid + it * 256;
          int row = c >> 3;
          int kc = (c & 7) << 3;
          int grow = m0 + row;
          long arow = grow;
          bool zero = false;
          if (TAPS > 1) {
            int s = grow & (S_ - 1);
            if (s + t - (TAPS - 1) < 0) zero = true;
            arow = (long)grow + t - (TAPS - 1);
          }
          uintx4 val;
          if (zero)
            val = uintx4{0u, 0u, 0u, 0u};
          else if (AF32)
            val = ld8_f32_bf(Ab32 + arow * lda + k0 + kc);
          else
            val = *(const uintx4*)(Ab16 + arow * lda + k0 + kc);
          *(uintx4*)&As[row * LDP + kc] = val;
        }
#pragma unroll
        for (int it = 0; it < BN * BK / 8 / 256; ++it) {
          int c = tid + it * 256;
          int row = c >> 3;
          int kc = (c & 7) << 3;
          long off = (long)(n0 + row) * ldw + (long)t * Kin + k0 + kc;
          uintx4 val;
          if (WF32)
            val = ld8_f32_bf(Wb32 + off);
          else
            val = *(const uintx4*)(Wb16 + off);
          *(uintx4*)&Bs[row * LDP + kc] = val;
        }
      }
      __syncthreads();
      // causal zero-pad fixup: only blocks at a sequence start, taps t<TAPS-1.
      // (block-uniform condition -> barrier is safe)
      if constexpr (GL && TAPS > 1) {
        if ((m0 & (S_ - 1)) == 0 && t < TAPS - 1) {
          int nz = TAPS - 1 - t;  // rows 0..nz-1 are pre-sequence -> zero
          if (tid < nz * 8) {
            int row = tid >> 3;
            int kc = (tid & 7) << 3;
            *(uintx4*)&As[row * LDP + kc] = uintx4{0u, 0u, 0u, 0u};
          }
          __syncthreads();
        }
      }
#pragma unroll
      for (int kk = 0; kk < BK; kk += 32) {
        short8 af[4], bfr[4];
#pragma unroll
        for (int r = 0; r < 4; ++r)
          af[r] = *(const short8*)&As[(wrow * 64 + r * 16 + lm) * LDP + kk + lk * 8];
#pragma unroll
        for (int c = 0; c < 4; ++c)
          bfr[c] = *(const short8*)&Bs[(wcol * 64 + c * 16 + lm) * LDP + kk + lk * 8];
#pragma unroll
        for (int r = 0; r < 4; ++r)
#pragma unroll
          for (int c = 0; c < 4; ++c)
            acc[r][c] = __builtin_amdgcn_mfma_f32_16x16x32_bf16(af[r], bfr[c], acc[r][c], 0, 0, 0);
      }
    }
  }

  float* Cf = (float*)Cout;
  u16* Cb = (u16*)Cout;
#pragma unroll
  for (int r = 0; r < 4; ++r) {
#pragma unroll
    for (int c = 0; c < 4; ++c) {
#pragma unroll
      for (int i = 0; i < 4; ++i) {
        int grow = m0 + wrow * 64 + r * 16 + lk * 4 + i;  // D row = (lane>>4)*4+reg
        int gcol = n0 + wcol * 64 + c * 16 + lm;          // D col = lane&15
        float v = acc[r][c][i];
        if (FLAGS & F_SCALE) v *= scale;
        if (FLAGS & F_BIAS) v += bias[gcol];
        long off = cOff + (long)grow * ldc + gcol;
        if (FLAGS & F_RESID) v += resid[off];
        if (FLAGS & F_RELU) v = v > 0.f ? v : 0.f;
        if (FLAGS & F_OUTF32)
          Cf[off] = v;
        else
          Cb[off] = f2bf(v);
      }
    }
  }
}

// fp32 -> bf16 elementwise, 8 elems/thread (n must be a multiple of 8)
__global__ void __launch_bounds__(256)
convert_bf16(const float* __restrict__ in, u16* __restrict__ out, long n) {
  long i = ((long)blockIdx.x * 256 + threadIdx.x) * 8;
  if (i >= n) return;
  *(uintx4*)(out + i) = ld8_f32_bf(in + i);
}

// In-place row softmax over fp32 scores; one block per row of 1024.
__global__ void __launch_bounds__(256)
softmax_kernel(float* __restrict__ attn) {
  long row = blockIdx.x;
  float* p = attn + row * (long)S_;
  int tid = threadIdx.x;
  float v[4];
  float mx = -3.4e38f;
#pragma unroll
  for (int i = 0; i < 4; ++i) {
    v[i] = p[tid + i * 256];
    mx = fmaxf(mx, v[i]);
  }
#pragma unroll
  for (int o = 32; o > 0; o >>= 1) mx = fmaxf(mx, __shfl_down(mx, o));
  __shared__ float sm[4];
  __shared__ float ss[4];
  if ((tid & 63) == 0) sm[tid >> 6] = mx;
  __syncthreads();
  mx = fmaxf(fmaxf(sm[0], sm[1]), fmaxf(sm[2], sm[3]));
  float s = 0.f;
#pragma unroll
  for (int i = 0; i < 4; ++i) {
    v[i] = __expf(v[i] - mx);
    s += v[i];
  }
#pragma unroll
  for (int o = 32; o > 0; o >>= 1) s += __shfl_down(s, o);
  if ((tid & 63) == 0) ss[tid >> 6] = s;
  __syncthreads();
  s = ss[0] + ss[1] + ss[2] + ss[3];
  float inv = 1.f / s;
#pragma unroll
  for (int i = 0; i < 4; ++i) p[tid + i * 256] = v[i] * inv;
}

// LayerNorm per row of E_=1024 fp32; optional second fp32 input added.
template <bool ADD2, bool STOREBF, bool STOREF32>
__global__ void __launch_bounds__(256)
ln_kernel(const float* __restrict__ in1, const float* __restrict__ in2,
          u16* __restrict__ outb, float* __restrict__ outf) {
  long row = blockIdx.x;
  const float* p1 = in1 + row * E_;
  int tid = threadIdx.x;
  float v[4];
  float s = 0.f, s2 = 0.f;
#pragma unroll
  for (int i = 0; i < 4; ++i) {
    float x = p1[tid + i * 256];
    if (ADD2) x += in2[row * E_ + tid + i * 256];
    v[i] = x;
    s += x;
    s2 += x * x;
  }
#pragma unroll
  for (int o = 32; o > 0; o >>= 1) {
    s += __shfl_down(s, o);
    s2 += __shfl_down(s2, o);
  }
  __shared__ float as_[4];
  __shared__ float bs_[4];
  if ((tid & 63) == 0) {
    as_[tid >> 6] = s;
    bs_[tid >> 6] = s2;
  }
  __syncthreads();
  s = as_[0] + as_[1] + as_[2] + as_[3];
  s2 = bs_[0] + bs_[1] + bs_[2] + bs_[3];
  float mean = s * (1.f / E_);
  float var = s2 * (1.f / E_) - mean * mean;
  float rstd = rsqrtf(var + 1e-5f);
#pragma unroll
  for (int i = 0; i < 4; ++i) {
    float y = (v[i] - mean) * rstd;
    if (STOREBF) outb[row * E_ + tid + i * 256] = f2bf(y);
    if (STOREF32) outf[row * E_ + tid + i * 256] = y;
  }
}

// v [B,S,H*DH] bf16 -> vT [B,H,DH,S] bf16
__global__ void __launch_bounds__(256)
transpose_v(const u16* __restrict__ v, u16* __restrict__ vT) {
  int bh = blockIdx.y;
  int b = bh / H_, h = bh % H_;
  int s0 = blockIdx.x * 64;
  __shared__ u16 t[64][65];
  int tid = threadIdx.x;
#pragma unroll
  for (int i = 0; i < 16; ++i) {
    int idx = tid + i * 256;
    int r = idx >> 6, c = idx & 63;  // r = s offset, c = d
    t[r][c] = v[(long)b * S_ * E_ + (long)(s0 + r) * E_ + h * DH_ + c];
  }
  __syncthreads();
#pragma unroll
  for (int i = 0; i < 16; ++i) {
    int idx = tid + i * 256;
    int d = idx >> 6, c = idx & 63;  // c = s offset
    vT[((long)bh * DH_ + d) * S_ + s0 + c] = t[c][d];
  }
}

// w fp32 [F, Cin, 3] -> wt bf16 [F, 3, Cin]
__global__ void __launch_bounds__(256)
transpose_w(const float* __restrict__ w, u16* __restrict__ wt, int F, int Cin) {
  long n = (long)F * Cin * KCONV;
  long i = (long)blockIdx.x * 256 + threadIdx.x;
  if (i >= n) return;
  int e = (int)(i % Cin);
  long tmp = i / Cin;
  int t = (int)(tmp % KCONV);
  int f = (int)(tmp / KCONV);
  wt[i] = f2bf(w[(long)f * Cin * KCONV + (long)e * KCONV + t]);
}

extern "C" void kernel_launch(void* const* d_in, const int* in_sizes, int n_in,
                              void* d_out, int out_size, void* d_ws, size_t ws_size,
                              hipStream_t stream) {
  const float* word = (const float*)d_in[0];
  const float* Wq = (const float*)d_in[1];
  const float* bq = (const float*)d_in[2];
  const float* Wk = (const float*)d_in[3];
  const float* bk = (const float*)d_in[4];
  const float* Wv = (const float*)d_in[5];
  const float* bv = (const float*)d_in[6];
  const float* Wo = (const float*)d_in[7];
  const float* bo = (const float*)d_in[8];
  const float* w1 = (const float*)d_in[9];
  const float* b1 = (const float*)d_in[10];
  const float* w2 = (const float*)d_in[11];
  const float* b2 = (const float*)d_in[12];

  // workspace layout (byte offsets, 1 MiB = 1048576); peak 168 MiB with reuse
  const long MB = 1048576L;
  char* ws = (char*)d_ws;
  u16* q_bf = (u16*)(ws + 0 * MB);       // 16 MiB, dead after scores
  u16* k_bf = (u16*)(ws + 16 * MB);      // 16 MiB, dead after scores
  u16* v_bf = (u16*)(ws + 32 * MB);      // 16 MiB, dead after transpose_v
  u16* vT = (u16*)(ws + 48 * MB);        // 16 MiB, dead after AV
  u16* outs_bf = (u16*)(ws + 64 * MB);   // 16 MiB, dead after proj
  u16* w1t = (u16*)(ws + 80 * MB);       // 12 MiB
  u16* w2t = (u16*)(ws + 92 * MB);       // 12 MiB
  float* z_f32 = (float*)(ws + 0 * MB);  // 32 MiB, reuses q/k (written in proj, after scores)
  u16* x_bf = (u16*)(ws + 32 * MB);      // 16 MiB, reuses v (written after transpose_v)
  float* x_f32 = (float*)(ws + 104 * MB);  // 32 MiB (written by LN, after proj)
  u16* h_bf = (u16*)(ws + 136 * MB);       // 32 MiB (written by conv1, after proj)
  float* y_f32 = (float*)(ws + 48 * MB);   // 32 MiB, reuses vT+outs (written in conv2)
  // bf16 pre-converted operands (enable the gload path); placed in regions
  // that are only written AFTER their last use:
  u16* word_bf = (u16*)(ws + 104 * MB);  // 16 MiB, in x_f32 slot (x_f32 written at LN)
  u16* wq_bf = (u16*)(ws + 136 * MB);    // 2 MiB each, in h_bf slot (h written at conv1)
  u16* wk_bf = (u16*)(ws + 138 * MB);
  u16* wv_bf = (u16*)(ws + 140 * MB);
  u16* wo_bf = (u16*)(ws + 142 * MB);

  float* out_f = (float*)d_out;
  float* attn_f = (float*)d_out + (long)B_ * S_ * E_;

  dim3 blk(256);

  // conv weight transpose + bf16 convert
  {
    long n1 = (long)DFF_ * E_ * KCONV;
    transpose_w<<<dim3((unsigned)((n1 + 255) / 256)), blk, 0, stream>>>(w1, w1t, DFF_, E_);
    long n2 = (long)E_ * DFF_ * KCONV;
    transpose_w<<<dim3((unsigned)((n2 + 255) / 256)), blk, 0, stream>>>(w2, w2t, E_, DFF_);
  }
  // fp32 -> bf16 operand pre-conversion (word + 4 linear weights)
  {
    long nw = (long)B_ * S_ * E_;
    convert_bf16<<<dim3((unsigned)(nw / 8 / 256)), blk, 0, stream>>>(word, word_bf, nw);
    long nl = (long)E_ * E_;
    unsigned gl = (unsigned)(nl / 8 / 256);
    convert_bf16<<<dim3(gl), blk, 0, stream>>>(Wq, wq_bf, nl);
    convert_bf16<<<dim3(gl), blk, 0, stream>>>(Wk, wk_bf, nl);
    convert_bf16<<<dim3(gl), blk, 0, stream>>>(Wv, wv_bf, nl);
    convert_bf16<<<dim3(gl), blk, 0, stream>>>(Wo, wo_bf, nl);
  }

  // QKV projections: [8192,1024] x [1024,1024]^T, all-bf16 -> gload path
  dim3 g_sq(E_ / 128, (B_ * S_) / 128, 1);
  gemm_kernel<2, 2, 1, F_BIAS, false, false><<<g_sq, blk, 0, stream>>>(
      word_bf, 0, 0, wq_bf, 0, 0, bq, nullptr, q_bf, 0, 0, 1, E_, E_, E_, E_, 1.f);
  gemm_kernel<2, 2, 1, F_BIAS, false, false><<<g_sq, blk, 0, stream>>>(
      word_bf, 0, 0, wk_bf, 0, 0, bk, nullptr, k_bf, 0, 0, 1, E_, E_, E_, E_, 1.f);
  gemm_kernel<2, 2, 1, F_BIAS, false, false><<<g_sq, blk, 0, stream>>>(
      word_bf, 0, 0, wv_bf, 0, 0, bv, nullptr, v_bf, 0, 0, 1, E_, E_, E_, E_, 1.f);

  // scores = q k^T / 8, batched over (b,h), fp32 into attn output region
  dim3 g_sc(S_ / 128, S_ / 128, B_ * H_);
  gemm_kernel<2, 2, 1, F_SCALE | F_OUTF32, false, false><<<g_sc, blk, 0, stream>>>(
      q_bf, (long)S_ * E_, DH_, k_bf, (long)S_ * E_, DH_, nullptr, nullptr,
      attn_f, (long)H_ * S_ * S_, (long)S_ * S_, H_, E_, E_, S_, DH_, 0.125f);

  // softmax in place (fp32)
  softmax_kernel<<<dim3(B_ * H_ * S_), blk, 0, stream>>>(attn_f);

  // v -> vT [B,H,DH,S]
  transpose_v<<<dim3(S_ / 64, B_ * H_), blk, 0, stream>>>(v_bf, vT);

  // outs = attn @ v  (BM=256, BN=64), A is fp32 attn -> register-staged path
  dim3 g_av(1, S_ / 256, B_ * H_);
  gemm_kernel<4, 1, 1, 0, true, false><<<g_av, blk, 0, stream>>>(
      attn_f, (long)H_ * S_ * S_, (long)S_ * S_, vT, (long)H_ * DH_ * S_, (long)DH_ * S_,
      nullptr, nullptr, outs_bf, (long)S_ * E_, DH_, H_, S_, S_, E_, S_, 1.f);

  // z = outs @ Wo^T + bo + word  (fp32 out); all-bf16 operands -> gload path
  gemm_kernel<2, 2, 1, F_BIAS | F_RESID | F_OUTF32, false, false><<<g_sq, blk, 0, stream>>>(
      outs_bf, 0, 0, wo_bf, 0, 0, bo, word, z_f32, 0, 0, 1, E_, E_, E_, E_, 1.f);

  // x = LN(z) -> bf16 + fp32
  ln_kernel<false, true, true><<<dim3(B_ * S_), blk, 0, stream>>>(z_f32, nullptr, x_bf, x_f32);

  // h = relu(conv1(x)) as 3-tap GEMM: [8192,2048] bf16
  dim3 g_c1(DFF_ / 128, (B_ * S_) / 128, 1);
  gemm_kernel<2, 2, 3, F_BIAS | F_RELU, false, false><<<g_c1, blk, 0, stream>>>(
      x_bf, 0, 0, w1t, 0, 0, b1, nullptr, h_bf, 0, 0, 1, E_, KCONV * E_, DFF_, E_, 1.f);

  // y = conv2(h) as 3-tap GEMM (fp32 out): [8192,1024]
  dim3 g_c2(E_ / 128, (B_ * S_) / 128, 1);
  gemm_kernel<2, 2, 3, F_BIAS | F_OUTF32, false, false><<<g_c2, blk, 0, stream>>>(
      h_bf, 0, 0, w2t, 0, 0, b2, nullptr, y_f32, 0, 0, 1, DFF_, KCONV * DFF_, E_, DFF_, 1.f);

  // out = LN(y + x) -> fp32 into d_out
  ln_kernel<true, false, true><<<dim3(B_ * S_), blk, 0, stream>>>(y_f32, x_f32, nullptr, out_f);
}

// Round 2
// 1409.898 us; speedup vs baseline: 1.3131x; 1.0860x over previous
//
#include <hip/hip_runtime.h>
#include <stdint.h>

#define B_ 8
#define S_ 1024
#define E_ 1024
#define H_ 16
#define DH_ 64
#define DFF_ 2048
#define KCONV 3

typedef unsigned short u16;
typedef __attribute__((ext_vector_type(8))) short short8;
typedef __attribute__((ext_vector_type(4))) float floatx4;
typedef __attribute__((ext_vector_type(4))) unsigned int uintx4;
typedef __attribute__((ext_vector_type(2))) unsigned int uintx2;

__device__ __forceinline__ u16 f2bf(float f) {
  unsigned int u = __builtin_bit_cast(unsigned int, f);
  u += 0x7FFFu + ((u >> 16) & 1u);
  return (u16)(u >> 16);
}
__device__ __forceinline__ float bf2f(u16 x) {
  unsigned int u = ((unsigned int)x) << 16;
  return __builtin_bit_cast(float, u);
}

// load 8 consecutive fp32, round-to-nearest-even to bf16, pack into 16B
__device__ __forceinline__ uintx4 ld8_f32_bf(const float* __restrict__ p) {
  floatx4 a = *(const floatx4*)p;
  floatx4 b = *(const floatx4*)(p + 4);
  uintx4 r;
  r.x = (unsigned)f2bf(a[0]) | ((unsigned)f2bf(a[1]) << 16);
  r.y = (unsigned)f2bf(a[2]) | ((unsigned)f2bf(a[3]) << 16);
  r.z = (unsigned)f2bf(b[0]) | ((unsigned)f2bf(b[1]) << 16);
  r.w = (unsigned)f2bf(b[2]) | ((unsigned)f2bf(b[3]) << 16);
  return r;
}

// async global->LDS, 16B per lane. LDS dest = wave-uniform base + lane*16.
__device__ __forceinline__ void gload16(const void* g, void* l) {
  __builtin_amdgcn_global_load_lds((__attribute__((address_space(1))) void*)g,
                                   (__attribute__((address_space(3))) void*)l,
                                   16, 0, 0);
}

// softmax a packed pair of bf16 raw scores: p = exp(s - m) * invl, repack bf16
__device__ __forceinline__ unsigned softpair(unsigned w, float m, float invl) {
  float a = bf2f((u16)(w & 0xffffu));
  float b = bf2f((u16)(w >> 16));
  a = __expf(a - m) * invl;
  b = __expf(b - m) * invl;
  return (unsigned)f2bf(a) | ((unsigned)f2bf(b) << 16);
}

enum { F_BIAS = 1, F_RELU = 2, F_RESID = 4, F_OUTF32 = 8, F_SCALE = 16 };

// NT GEMM: D[m][n] = scale * sum_k A[m][k] * W[n][k] (+bias[n]) (+resid[m][n])
// AF32/WF32: operand stored fp32, converted bf16 during register LDS staging.
// ASOFT: A is bf16 RAW attention scores; staging applies p=exp(s-m)*invl using
//        per-row stats (astats[z*S + row] = {m, 1/l}) -- fuses softmax into AV.
// Operand-side gload: A uses global_load_lds iff !AF32 && !ASOFT; B iff !WF32.
// gload sides use LINEAR LDS (LDP=64; m97 regime, gload gain dominates the
// read conflicts); register-staged sides keep the +8 pad.
// TAPS>1: causal-conv mode, A row for tap t is (s + t - (TAPS-1)); pre-sequence
// rows are zeroed after staging (gload can't zero-fill; stale loads stay inside
// the workspace so they're safe to fetch then overwrite).
// Batched via blockIdx.z: base offsets (z/zdiv)*S1 + (z%zdiv)*S2.
template <int WR, int WC, int TAPS, int FLAGS, bool AF32, bool WF32, bool ASOFT>
__global__ void __launch_bounds__(256, 2)
gemm_kernel(const void* __restrict__ A, long aS1, long aS2,
            const void* __restrict__ W, long wS1, long wS2,
            const float* __restrict__ bias, const float* __restrict__ resid,
            const float2* __restrict__ astats,
            void* __restrict__ Cout, long cS1, long cS2,
            int zdiv, int lda, int ldw, int ldc, int Kin, float scale) {
  constexpr bool GLA = !AF32 && !ASOFT;
  constexpr bool GLB = !WF32;
  constexpr int BM = WR * 64, BN = WC * 64, BK = 64;
  constexpr int LDPA = GLA ? BK : BK + 8;
  constexpr int LDPB = GLB ? BK : BK + 8;
  __shared__ __align__(16) u16 As[BM * LDPA];
  __shared__ __align__(16) u16 Bs[BN * LDPB];

  const int z = blockIdx.z;
  const int zq = z / zdiv, zr = z % zdiv;
  const u16* Ab16 = (const u16*)A + zq * aS1 + zr * aS2;
  const float* Ab32 = (const float*)A + zq * aS1 + zr * aS2;
  const u16* Wb16 = (const u16*)W + zq * wS1 + zr * wS2;
  const float* Wb32 = (const float*)W + zq * wS1 + zr * wS2;
  const long cOff = zq * cS1 + zr * cS2;

  const int m0 = blockIdx.y * BM;
  const int n0 = blockIdx.x * BN;
  const int tid = threadIdx.x;
  const int lane = tid & 63;
  const int wave = tid >> 6;
  const int wrow = wave / WC;
  const int wcol = wave % WC;
  const int lm = lane & 15;  // MFMA m/n index
  const int lk = lane >> 4;  // MFMA k-quad

  floatx4 acc[4][4];
#pragma unroll
  for (int r = 0; r < 4; ++r)
#pragma unroll
    for (int c = 0; c < 4; ++c) acc[r][c] = floatx4{0.f, 0.f, 0.f, 0.f};

  for (int t = 0; t < TAPS; ++t) {
    for (int k0 = 0; k0 < Kin; k0 += BK) {
      __syncthreads();
      // ---- stage A tile (BM x BK) ----
      if constexpr (GLA) {
#pragma unroll
        for (int it = 0; it < BM * BK / 8 / 256; ++it) {
          int c = tid + it * 256;
          int row = c >> 3;
          int kc = (c & 7) << 3;
          long arow = m0 + row;
          if (TAPS > 1) arow += t - (TAPS - 1);  // may go <0: stale-but-safe, zeroed below
          gload16(Ab16 + arow * (long)lda + k0 + kc,
                  (char*)As + it * 4096 + wave * 1024);
        }
      } else {
#pragma unroll
        for (int it = 0; it < BM * BK / 8 / 256; ++it) {
          int c = tid + it * 256;
          int row = c >> 3;
          int kc = (c & 7) << 3;
          int grow = m0 + row;
          long arow = grow;
          bool zero = false;
          if (TAPS > 1) {
            int s = grow & (S_ - 1);
            if (s + t - (TAPS - 1) < 0) zero = true;
            arow = (long)grow + t - (TAPS - 1);
          }
          uintx4 val;
          if (zero)
            val = uintx4{0u, 0u, 0u, 0u};
          else if (ASOFT) {
            uintx4 raw = *(const uintx4*)(Ab16 + arow * lda + k0 + kc);
            float2 st = astats[(long)z * S_ + grow];
            val.x = softpair(raw.x, st.x, st.y);
            val.y = softpair(raw.y, st.x, st.y);
            val.z = softpair(raw.z, st.x, st.y);
            val.w = softpair(raw.w, st.x, st.y);
          } else if (AF32)
            val = ld8_f32_bf(Ab32 + arow * lda + k0 + kc);
          else
            val = *(const uintx4*)(Ab16 + arow * lda + k0 + kc);
          *(uintx4*)&As[row * LDPA + kc] = val;
        }
      }
      // ---- stage W tile (BN x BK) ----
      if constexpr (GLB) {
#pragma unroll
        for (int it = 0; it < BN * BK / 8 / 256; ++it) {
          int c = tid + it * 256;
          int row = c >> 3;
          int kc = (c & 7) << 3;
          long off = (long)(n0 + row) * ldw + (long)t * Kin + k0 + kc;
          gload16(Wb16 + off, (char*)Bs + it * 4096 + wave * 1024);
        }
      } else {
#pragma unroll
        for (int it = 0; it < BN * BK / 8 / 256; ++it) {
          int c = tid + it * 256;
          int row = c >> 3;
          int kc = (c & 7) << 3;
          long off = (long)(n0 + row) * ldw + (long)t * Kin + k0 + kc;
          uintx4 val;
          if (WF32)
            val = ld8_f32_bf(Wb32 + off);
          else
            val = *(const uintx4*)(Wb16 + off);
          *(uintx4*)&Bs[row * LDPB + kc] = val;
        }
      }
      __syncthreads();
      // causal zero-pad fixup: only blocks at a sequence start, taps t<TAPS-1.
      // (block-uniform condition -> barrier is safe)
      if constexpr (GLA && TAPS > 1) {
        if ((m0 & (S_ - 1)) == 0 && t < TAPS - 1) {
          int nz = TAPS - 1 - t;  // rows 0..nz-1 are pre-sequence -> zero
          if (tid < nz * 8) {
            int row = tid >> 3;
            int kc = (tid & 7) << 3;
            *(uintx4*)&As[row * LDPA + kc] = uintx4{0u, 0u, 0u, 0u};
          }
          __syncthreads();
        }
      }
#pragma unroll
      for (int kk = 0; kk < BK; kk += 32) {
        short8 af[4], bfr[4];
#pragma unroll
        for (int r = 0; r < 4; ++r)
          af[r] = *(const short8*)&As[(wrow * 64 + r * 16 + lm) * LDPA + kk + lk * 8];
#pragma unroll
        for (int c = 0; c < 4; ++c)
          bfr[c] = *(const short8*)&Bs[(wcol * 64 + c * 16 + lm) * LDPB + kk + lk * 8];
#pragma unroll
        for (int r = 0; r < 4; ++r)
#pragma unroll
          for (int c = 0; c < 4; ++c)
            acc[r][c] = __builtin_amdgcn_mfma_f32_16x16x32_bf16(af[r], bfr[c], acc[r][c], 0, 0, 0);
      }
    }
  }

  float* Cf = (float*)Cout;
  u16* Cb = (u16*)Cout;
#pragma unroll
  for (int r = 0; r < 4; ++r) {
#pragma unroll
    for (int c = 0; c < 4; ++c) {
#pragma unroll
      for (int i = 0; i < 4; ++i) {
        int grow = m0 + wrow * 64 + r * 16 + lk * 4 + i;  // D row = (lane>>4)*4+reg
        int gcol = n0 + wcol * 64 + c * 16 + lm;          // D col = lane&15
        float v = acc[r][c][i];
        if (FLAGS & F_SCALE) v *= scale;
        if (FLAGS & F_BIAS) v += bias[gcol];
        long off = cOff + (long)grow * ldc + gcol;
        if (FLAGS & F_RESID) v += resid[off];
        if (FLAGS & F_RELU) v = v > 0.f ? v : 0.f;
        if (FLAGS & F_OUTF32)
          Cf[off] = v;
        else
          Cb[off] = f2bf(v);
      }
    }
  }
}

// fp32 -> bf16 elementwise, 8 elems/thread (n must be a multiple of 8)
__global__ void __launch_bounds__(256)
convert_bf16(const float* __restrict__ in, u16* __restrict__ out, long n) {
  long i = ((long)blockIdx.x * 256 + threadIdx.x) * 8;
  if (i >= n) return;
  *(uintx4*)(out + i) = ld8_f32_bf(in + i);
}

// In-place row softmax over fp32 scores; one block per row of 1024. (fallback path)
__global__ void __launch_bounds__(256)
softmax_kernel(float* __restrict__ attn) {
  long row = blockIdx.x;
  float* p = attn + row * (long)S_;
  int tid = threadIdx.x;
  float v[4];
  float mx = -3.4e38f;
#pragma unroll
  for (int i = 0; i < 4; ++i) {
    v[i] = p[tid + i * 256];
    mx = fmaxf(mx, v[i]);
  }
#pragma unroll
  for (int o = 32; o > 0; o >>= 1) mx = fmaxf(mx, __shfl_down(mx, o));
  __shared__ float sm[4];
  __shared__ float ss[4];
  if ((tid & 63) == 0) sm[tid >> 6] = mx;
  __syncthreads();
  mx = fmaxf(fmaxf(sm[0], sm[1]), fmaxf(sm[2], sm[3]));
  float s = 0.f;
#pragma unroll
  for (int i = 0; i < 4; ++i) {
    v[i] = __expf(v[i] - mx);
    s += v[i];
  }
#pragma unroll
  for (int o = 32; o > 0; o >>= 1) s += __shfl_down(s, o);
  if ((tid & 63) == 0) ss[tid >> 6] = s;
  __syncthreads();
  s = ss[0] + ss[1] + ss[2] + ss[3];
  float inv = 1.f / s;
#pragma unroll
  for (int i = 0; i < 4; ++i) p[tid + i * 256] = v[i] * inv;
}

// Read bf16 raw scores row, compute (m, l), write normalized fp32 attn row
// to d_out and {m, 1/l} stats for the fused AV kernel. One block per row.
__global__ void __launch_bounds__(256)
softmax_finalize(const u16* __restrict__ raw, float* __restrict__ attn,
                 float2* __restrict__ stats) {
  long row = blockIdx.x;
  const u16* p = raw + row * (long)S_;
  int tid = threadIdx.x;
  uintx2 w = *(const uintx2*)(p + tid * 4);
  float v[4];
  v[0] = bf2f((u16)(w.x & 0xffffu));
  v[1] = bf2f((u16)(w.x >> 16));
  v[2] = bf2f((u16)(w.y & 0xffffu));
  v[3] = bf2f((u16)(w.y >> 16));
  float mx = fmaxf(fmaxf(v[0], v[1]), fmaxf(v[2], v[3]));
#pragma unroll
  for (int o = 32; o > 0; o >>= 1) mx = fmaxf(mx, __shfl_down(mx, o));
  __shared__ float sm[4];
  __shared__ float ss[4];
  if ((tid & 63) == 0) sm[tid >> 6] = mx;
  __syncthreads();
  mx = fmaxf(fmaxf(sm[0], sm[1]), fmaxf(sm[2], sm[3]));
  float s = 0.f;
#pragma unroll
  for (int i = 0; i < 4; ++i) {
    v[i] = __expf(v[i] - mx);
    s += v[i];
  }
#pragma unroll
  for (int o = 32; o > 0; o >>= 1) s += __shfl_down(s, o);
  if ((tid & 63) == 0) ss[tid >> 6] = s;
  __syncthreads();
  s = ss[0] + ss[1] + ss[2] + ss[3];
  float inv = 1.f / s;
  floatx4 outv;
#pragma unroll
  for (int i = 0; i < 4; ++i) outv[i] = v[i] * inv;
  *(floatx4*)(attn + row * (long)S_ + tid * 4) = outv;
  if (tid == 0) stats[row] = make_float2(mx, inv);
}

// LayerNorm per row of E_=1024 fp32; optional second fp32 input added.
template <bool ADD2, bool STOREBF, bool STOREF32>
__global__ void __launch_bounds__(256)
ln_kernel(const float* __restrict__ in1, const float* __restrict__ in2,
          u16* __restrict__ outb, float* __restrict__ outf) {
  long row = blockIdx.x;
  const float* p1 = in1 + row * E_;
  int tid = threadIdx.x;
  float v[4];
  float s = 0.f, s2 = 0.f;
#pragma unroll
  for (int i = 0; i < 4; ++i) {
    float x = p1[tid + i * 256];
    if (ADD2) x += in2[row * E_ + tid + i * 256];
    v[i] = x;
    s += x;
    s2 += x * x;
  }
#pragma unroll
  for (int o = 32; o > 0; o >>= 1) {
    s += __shfl_down(s, o);
    s2 += __shfl_down(s2, o);
  }
  __shared__ float as_[4];
  __shared__ float bs_[4];
  if ((tid & 63) == 0) {
    as_[tid >> 6] = s;
    bs_[tid >> 6] = s2;
  }
  __syncthreads();
  s = as_[0] + as_[1] + as_[2] + as_[3];
  s2 = bs_[0] + bs_[1] + bs_[2] + bs_[3];
  float mean = s * (1.f / E_);
  float var = s2 * (1.f / E_) - mean * mean;
  float rstd = rsqrtf(var + 1e-5f);
#pragma unroll
  for (int i = 0; i < 4; ++i) {
    float y = (v[i] - mean) * rstd;
    if (STOREBF) outb[row * E_ + tid + i * 256] = f2bf(y);
    if (STOREF32) outf[row * E_ + tid + i * 256] = y;
  }
}

// v [B,S,H*DH] bf16 -> vT [B,H,DH,S] bf16
__global__ void __launch_bounds__(256)
transpose_v(const u16* __restrict__ v, u16* __restrict__ vT) {
  int bh = blockIdx.y;
  int b = bh / H_, h = bh % H_;
  int s0 = blockIdx.x * 64;
  __shared__ u16 t[64][65];
  int tid = threadIdx.x;
#pragma unroll
  for (int i = 0; i < 16; ++i) {
    int idx = tid + i * 256;
    int r = idx >> 6, c = idx & 63;  // r = s offset, c = d
    t[r][c] = v[(long)b * S_ * E_ + (long)(s0 + r) * E_ + h * DH_ + c];
  }
  __syncthreads();
#pragma unroll
  for (int i = 0; i < 16; ++i) {
    int idx = tid + i * 256;
    int d = idx >> 6, c = idx & 63;  // c = s offset
    vT[((long)bh * DH_ + d) * S_ + s0 + c] = t[c][d];
  }
}

// w fp32 [F, Cin, 3] -> wt bf16 [F, 3, Cin]
__global__ void __launch_bounds__(256)
transpose_w(const float* __restrict__ w, u16* __restrict__ wt, int F, int Cin) {
  long n = (long)F * Cin * KCONV;
  long i = (long)blockIdx.x * 256 + threadIdx.x;
  if (i >= n) return;
  int e = (int)(i % Cin);
  long tmp = i / Cin;
  int t = (int)(tmp % KCONV);
  int f = (int)(tmp / KCONV);
  wt[i] = f2bf(w[(long)f * Cin * KCONV + (long)e * KCONV + t]);
}

extern "C" void kernel_launch(void* const* d_in, const int* in_sizes, int n_in,
                              void* d_out, int out_size, void* d_ws, size_t ws_size,
                              hipStream_t stream) {
  const float* word = (const float*)d_in[0];
  const float* Wq = (const float*)d_in[1];
  const float* bq = (const float*)d_in[2];
  const float* Wk = (const float*)d_in[3];
  const float* bk = (const float*)d_in[4];
  const float* Wv = (const float*)d_in[5];
  const float* bv = (const float*)d_in[6];
  const float* Wo = (const float*)d_in[7];
  const float* bo = (const float*)d_in[8];
  const float* w1 = (const float*)d_in[9];
  const float* b1 = (const float*)d_in[10];
  const float* w2 = (const float*)d_in[11];
  const float* b2 = (const float*)d_in[12];

  // workspace layout (byte offsets, 1 MiB = 1048576)
  const long MB = 1048576L;
  char* ws = (char*)d_ws;
  u16* q_bf = (u16*)(ws + 0 * MB);       // 16 MiB, dead after scores
  u16* k_bf = (u16*)(ws + 16 * MB);      // 16 MiB, dead after scores
  u16* v_bf = (u16*)(ws + 32 * MB);      // 16 MiB, dead after transpose_v
  u16* vT = (u16*)(ws + 48 * MB);        // 16 MiB, dead after AV
  u16* outs_bf = (u16*)(ws + 64 * MB);   // 16 MiB, dead after proj
  u16* w1t = (u16*)(ws + 80 * MB);       // 12 MiB
  u16* w2t = (u16*)(ws + 92 * MB);       // 12 MiB
  float* z_f32 = (float*)(ws + 0 * MB);  // 32 MiB, reuses q/k (written in proj, after scores)
  u16* x_bf = (u16*)(ws + 32 * MB);      // 16 MiB, reuses v (written after transpose_v)
  float* x_f32 = (float*)(ws + 104 * MB);  // 32 MiB (written by LN, after proj)
  u16* h_bf = (u16*)(ws + 136 * MB);       // 32 MiB (written by conv1, after AV/proj)
  float* y_f32 = (float*)(ws + 48 * MB);   // 32 MiB, reuses vT+outs (written in conv2)
  // bf16 pre-converted operands (enable the gload path); placed in regions
  // that are only written AFTER their last use:
  u16* word_bf = (u16*)(ws + 104 * MB);  // 16 MiB, in x_f32 slot (x_f32 written at LN)
  u16* wq_bf = (u16*)(ws + 136 * MB);    // 2 MiB each, in h_bf slot (h written at conv1)
  u16* wk_bf = (u16*)(ws + 138 * MB);
  u16* wv_bf = (u16*)(ws + 140 * MB);
  u16* wo_bf = (u16*)(ws + 142 * MB);
  // optimized-attention extras (guarded on ws_size):
  //   raw bf16 scores 256 MiB at 144..400 (alive scores->AV; h_bf@136-168 only
  //   written at conv1, after AV -- no overlap in time), stats 1 MiB at 400.
  u16* raw_bf = (u16*)(ws + 144 * MB);
  float2* stats = (float2*)(ws + 400 * MB);
  const bool big_ws = ws_size >= (size_t)(402 * MB);

  float* out_f = (float*)d_out;
  float* attn_f = (float*)d_out + (long)B_ * S_ * E_;

  dim3 blk(256);

  // conv weight transpose + bf16 convert
  {
    long n1 = (long)DFF_ * E_ * KCONV;
    transpose_w<<<dim3((unsigned)((n1 + 255) / 256)), blk, 0, stream>>>(w1, w1t, DFF_, E_);
    long n2 = (long)E_ * DFF_ * KCONV;
    transpose_w<<<dim3((unsigned)((n2 + 255) / 256)), blk, 0, stream>>>(w2, w2t, E_, DFF_);
  }
  // fp32 -> bf16 operand pre-conversion (word + 4 linear weights)
  {
    long nw = (long)B_ * S_ * E_;
    convert_bf16<<<dim3((unsigned)(nw / 8 / 256)), blk, 0, stream>>>(word, word_bf, nw);
    long nl = (long)E_ * E_;
    unsigned gl = (unsigned)(nl / 8 / 256);
    convert_bf16<<<dim3(gl), blk, 0, stream>>>(Wq, wq_bf, nl);
    convert_bf16<<<dim3(gl), blk, 0, stream>>>(Wk, wk_bf, nl);
    convert_bf16<<<dim3(gl), blk, 0, stream>>>(Wv, wv_bf, nl);
    convert_bf16<<<dim3(gl), blk, 0, stream>>>(Wo, wo_bf, nl);
  }

  // QKV projections: [8192,1024] x [1024,1024]^T, all-bf16 -> gload path
  dim3 g_sq(E_ / 128, (B_ * S_) / 128, 1);
  gemm_kernel<2, 2, 1, F_BIAS, false, false, false><<<g_sq, blk, 0, stream>>>(
      word_bf, 0, 0, wq_bf, 0, 0, bq, nullptr, nullptr, q_bf, 0, 0, 1, E_, E_, E_, E_, 1.f);
  gemm_kernel<2, 2, 1, F_BIAS, false, false, false><<<g_sq, blk, 0, stream>>>(
      word_bf, 0, 0, wk_bf, 0, 0, bk, nullptr, nullptr, k_bf, 0, 0, 1, E_, E_, E_, E_, 1.f);
  gemm_kernel<2, 2, 1, F_BIAS, false, false, false><<<g_sq, blk, 0, stream>>>(
      word_bf, 0, 0, wv_bf, 0, 0, bv, nullptr, nullptr, v_bf, 0, 0, 1, E_, E_, E_, E_, 1.f);

  dim3 g_sc(S_ / 128, S_ / 128, B_ * H_);
  dim3 g_av(1, S_ / 256, B_ * H_);

  // v -> vT [B,H,DH,S] (independent of scores; do it early)
  transpose_v<<<dim3(S_ / 64, B_ * H_), blk, 0, stream>>>(v_bf, vT);

  if (big_ws) {
    // scores = q k^T / 8 -> RAW bf16 into workspace (half the write traffic)
    gemm_kernel<2, 2, 1, F_SCALE, false, false, false><<<g_sc, blk, 0, stream>>>(
        q_bf, (long)S_ * E_, DH_, k_bf, (long)S_ * E_, DH_, nullptr, nullptr, nullptr,
        raw_bf, (long)H_ * S_ * S_, (long)S_ * S_, H_, E_, E_, S_, DH_, 0.125f);

    // row stats + normalized fp32 attn to d_out
    softmax_finalize<<<dim3(B_ * H_ * S_), blk, 0, stream>>>(raw_bf, attn_f, stats);

    // outs = softmax(raw) @ v with softmax fused into A-staging (bf16 reads)
    gemm_kernel<4, 1, 1, 0, false, false, true><<<g_av, blk, 0, stream>>>(
        raw_bf, (long)H_ * S_ * S_, (long)S_ * S_, vT, (long)H_ * DH_ * S_, (long)DH_ * S_,
        nullptr, nullptr, stats, outs_bf, (long)S_ * E_, DH_, H_, S_, S_, E_, S_, 1.f);
  } else {
    // fallback (small workspace): fp32 scores in d_out, in-place softmax
    gemm_kernel<2, 2, 1, F_SCALE | F_OUTF32, false, false, false><<<g_sc, blk, 0, stream>>>(
        q_bf, (long)S_ * E_, DH_, k_bf, (long)S_ * E_, DH_, nullptr, nullptr, nullptr,
        attn_f, (long)H_ * S_ * S_, (long)S_ * S_, H_, E_, E_, S_, DH_, 0.125f);
    softmax_kernel<<<dim3(B_ * H_ * S_), blk, 0, stream>>>(attn_f);
    gemm_kernel<4, 1, 1, 0, true, false, false><<<g_av, blk, 0, stream>>>(
        attn_f, (long)H_ * S_ * S_, (long)S_ * S_, vT, (long)H_ * DH_ * S_, (long)DH_ * S_,
        nullptr, nullptr, nullptr, outs_bf, (long)S_ * E_, DH_, H_, S_, S_, E_, S_, 1.f);
  }

  // z = outs @ Wo^T + bo + word  (fp32 out); all-bf16 operands -> gload path
  gemm_kernel<2, 2, 1, F_BIAS | F_RESID | F_OUTF32, false, false, false><<<g_sq, blk, 0, stream>>>(
      outs_bf, 0, 0, wo_bf, 0, 0, bo, word, nullptr, z_f32, 0, 0, 1, E_, E_, E_, E_, 1.f);

  // x = LN(z) -> bf16 + fp32
  ln_kernel<false, true, true><<<dim3(B_ * S_), blk, 0, stream>>>(z_f32, nullptr, x_bf, x_f32);

  // h = relu(conv1(x)) as 3-tap GEMM: [8192,2048] bf16
  dim3 g_c1(DFF_ / 128, (B_ * S_) / 128, 1);
  gemm_kernel<2, 2, 3, F_BIAS | F_RELU, false, false, false><<<g_c1, blk, 0, stream>>>(
      x_bf, 0, 0, w1t, 0, 0, b1, nullptr, nullptr, h_bf, 0, 0, 1, E_, KCONV * E_, DFF_, E_, 1.f);

  // y = conv2(h) as 3-tap GEMM (fp32 out): [8192,1024]
  dim3 g_c2(E_ / 128, (B_ * S_) / 128, 1);
  gemm_kernel<2, 2, 3, F_BIAS | F_OUTF32, false, false, false><<<g_c2, blk, 0, stream>>>(
      h_bf, 0, 0, w2t, 0, 0, b2, nullptr, nullptr, y_f32, 0, 0, 1, DFF_, KCONV * DFF_, E_, DFF_, 1.f);

  // out = LN(y + x) -> fp32 into d_out
  ln_kernel<true, false, true><<<dim3(B_ * S_), blk, 0, stream>>>(y_f32, x_f32, nullptr, out_f);
}